// Round 8
// baseline (155.741 us; speedup 1.0000x reference)
//
#include <hip/hip_runtime.h>
#include <hip/hip_bf16.h>

#define T_DIM 4096
#define B_DIM 32
#define H_DIM 128
#define M_DIM (T_DIM * B_DIM)        // 131072 GEMM rows (t*B + b)
#define G_DIM 512                    // 4*H gate columns
#define TBH   ((long)M_DIM * H_DIM)  // 16777216 output elements for `outputs`

#define RPB    512                   // rows per persistent block: 256 blocks = 1 block/CU
#define NCHUNK (RPB / 32)            // 16 chunks of 32 rows
#define LSTR   136                   // LDS row stride in shorts (128 + 8 pad = 272 B, bank-balanced)
#define LBUF   (32 * LSTR)           // one staging buffer (shorts)
#define IGSTR  20                    // ig row stride in floats (2-way bank alias only = free)
#define IGPAIR (32 * IGSTR)          // 640 floats per pair per buffer
#define IGBUF  (8 * IGPAIR)          // 5120 floats per buffer

typedef __attribute__((ext_vector_type(8))) short short8;    // 8 bf16 = 4 VGPRs (MFMA A/B frag)
typedef __attribute__((ext_vector_type(4))) short short4v;   // 4 bf16 = 8 bytes
typedef __attribute__((ext_vector_type(4))) float floatx4;   // MFMA C/D frag

__device__ __forceinline__ unsigned short f2bf_rne(float x) {
    union { float f; unsigned int u; } v; v.f = x;
    unsigned int r = v.u + 0x7FFFu + ((v.u >> 16) & 1u);   // round-nearest-even
    return (unsigned short)(r >> 16);
}
__device__ __forceinline__ unsigned short f2bf_rh(float x) {
    union { float f; unsigned int u; } v; v.f = x;
    return (unsigned short)((v.u + 0x8000u) >> 16);        // round-half-up (cheap, ~unbiased)
}
__device__ __forceinline__ float ex2(float x) { return __builtin_amdgcn_exp2f(x); }   // v_exp_f32
__device__ __forceinline__ float rcpf(float x) { return __builtin_amdgcn_rcpf(x); }   // v_rcp_f32
__device__ __forceinline__ short8 pack8(float4 f0, float4 f1) {
    short8 s;
    s[0] = (short)f2bf_rh(f0.x); s[1] = (short)f2bf_rh(f0.y);
    s[2] = (short)f2bf_rh(f0.z); s[3] = (short)f2bf_rh(f0.w);
    s[4] = (short)f2bf_rh(f1.x); s[5] = (short)f2bf_rh(f1.y);
    s[6] = (short)f2bf_rh(f1.z); s[7] = (short)f2bf_rh(f1.w);
    return s;
}

// blocks 0..31:  hh[b][g] = h0[b,:]·W_hh[g,:] + b_ih[g] + b_hh[g]   (fp32, 32x512)
// blocks 32..95: W_ih fp32 -> bf16 (RNE) into ws
__global__ void prep(const float* __restrict__ h0,
                     const float* __restrict__ W_hh,
                     const float* __restrict__ b_ih,
                     const float* __restrict__ b_hh,
                     const float* __restrict__ W_ih,
                     unsigned short* __restrict__ Wb,
                     float* __restrict__ hh) {
    const int tid = threadIdx.x;
    if (blockIdx.x < 32) {
        __shared__ float h0s[128];
        const int b = blockIdx.x;
        if (tid < 128) h0s[tid] = h0[b * 128 + tid];
        __syncthreads();
        for (int g = tid; g < G_DIM; g += 256) {
            float acc = b_ih[g] + b_hh[g];
            const float* wr = W_hh + g * 128;
            #pragma unroll 8
            for (int k = 0; k < 128; ++k) acc += wr[k] * h0s[k];
            hh[b * G_DIM + g] = acc;
        }
    } else {
        const int e = ((blockIdx.x - 32) * 256 + tid) * 4;   // 64*256*4 = 65536 elements
        float4 f = *(const float4*)(W_ih + e);
        short4v s;
        s[0] = (short)f2bf_rne(f.x); s[1] = (short)f2bf_rne(f.y);
        s[2] = (short)f2bf_rne(f.z); s[3] = (short)f2bf_rne(f.w);
        *(short4v*)(Wb + e) = s;
    }
}

// GATE-SPLIT WAVE-PAIR kernel: 256 blocks x 1024 threads (16 waves -> 4 waves/SIMD forced;
// a 1024-thread block can only launch at VGPR<=128, and the halved per-wave footprint
// [wf 32, acc 16, hhf 16] makes that the natural allocation, not a spill).
// Wave pair (w, w+8) owns h-cols [p*16,p*16+16), p = w&7.
//   wave A (w<8): gates {0=i, 2=g}; computes ig = sigm(i)*tanh(g) -> LDS handoff (3 trans),
//                 plus all X staging (pack8) and 2-chunk-deep global prefetch.
//   wave B (w>=8): gates {1=f, 3=o}; reads ig, computes cc/h (5 trans), all global stores.
// One barrier per chunk; ig double-buffered so A's writes (pre-barrier, chunk c) never
// collide with B's reads (post-barrier, chunk c): the same buffer is rewritten only in
// chunk c+2, after barrier(c+1), which B passes only after finishing its chunk-c reads.
// Round-robin wave->SIMD => each SIMD hosts 2 A + 2 B at anti-phase => stall fill + 2x waves.
__global__ __launch_bounds__(1024) void lstm_main(
    const float* __restrict__ X,              // [M,128] fp32 input rows
    const unsigned short* __restrict__ W,     // [512,128] bf16 W_ih (pre-converted, B^T layout)
    const float* __restrict__ hh,             // [32,512] fp32 precomputed
    const float* __restrict__ c0,             // [32,128] fp32
    const float* __restrict__ noise,          // [32,128] fp32
    float* __restrict__ out)                  // fp32: outputs[M*128], h_last[4096], c_last[4096]
{
    __shared__ unsigned short Xs[2 * LBUF];   // 2 x 32 x 136 bf16 = 17408 B
    __shared__ float igs[2 * IGBUF];          // 2 x 8 pairs x 32 x 20 f32 = 40960 B

    const int tid  = threadIdx.x;
    const int w    = tid >> 6;       // wave 0..15
    const int lane = tid & 63;
    const int q    = lane >> 4;      // quad 0..3
    const int lr   = lane & 15;
    const bool isA = (w < 8);
    const int p    = w & 7;          // pair id
    const int bsel = w >> 3;         // 0 for A, 1 for B
    const int hcol = (p << 4) + lr;  // this pair's h-column, 0..127
    const long row0 = (long)blockIdx.x * RPB;

    // ---- one-time: W fragments for THIS WAVE'S 2 gates (j=0 -> gate 2j+bsel)
    short8 wf[2][4];                 // 8 frags = 32 VGPRs
    #pragma unroll
    for (int j = 0; j < 2; ++j)
        #pragma unroll
        for (int kt = 0; kt < 4; ++kt)
            wf[j][kt] = *(const short8*)(W + (((j << 1) | bsel) * 128 + hcol) * 128 + kt * 32 + q * 8);

    // ---- one-time: hh seeds for the 2 gates; B also loads c0/noise
    floatx4 hhf[2][2];
    #pragma unroll
    for (int mt = 0; mt < 2; ++mt)
        #pragma unroll
        for (int j = 0; j < 2; ++j) {
            floatx4 a;
            #pragma unroll
            for (int r = 0; r < 4; ++r)
                a[r] = hh[(mt * 16 + q * 4 + r) * G_DIM + ((j << 1) | bsel) * 128 + hcol];
            hhf[mt][j] = a;
        }
    float c0v[2][4], nzv[2][4];
    if (!isA) {
        #pragma unroll
        for (int mt = 0; mt < 2; ++mt)
            #pragma unroll
            for (int r = 0; r < 4; ++r) {
                const int b = mt * 16 + q * 4 + r;
                c0v[mt][r] = c0[b * 128 + hcol];
                nzv[mt][r] = noise[b * 128 + hcol];
            }
    }

    // ---- staging (A waves = tid 0..511): thread handles 8 consecutive X elements per chunk
    const int srow = tid >> 4;            // 0..31 (valid for tid<512)
    const int scol = (tid & 15) << 3;     // 0,8,...,120
    const float* xsrc = X + (row0 + srow) * 128 + scol;
    unsigned short* lws = &Xs[srow * LSTR + scol];

    float4 p0 = {}, p1 = {}, n0 = {}, n1 = {};
    if (isA) {
        float4 f0 = *(const float4*)(xsrc);
        float4 f1 = *(const float4*)(xsrc + 4);
        *(short8*)lws = pack8(f0, f1);
        p0 = *(const float4*)(xsrc + 4096);       // chunk 1
        p1 = *(const float4*)(xsrc + 4096 + 4);
    }
    __syncthreads();

    const float K1 = 1.44269504f;        // log2(e)
    const float K2 = 2.88539008f;        // 2*log2(e)

    for (int c = 0; c < NCHUNK; ++c) {
        // ---- phase 1 (all waves): A frags from LDS, 16 MFMAs (2 gates x 2 mt x 4 kt)
        const unsigned short* rb = &Xs[(c & 1) * LBUF];
        short8 af[2][4];
        #pragma unroll
        for (int mt = 0; mt < 2; ++mt)
            #pragma unroll
            for (int kt = 0; kt < 4; ++kt)
                af[mt][kt] = *(const short8*)(rb + (mt * 16 + lr) * LSTR + kt * 32 + q * 8);

        floatx4 acc[2][2];
        #pragma unroll
        for (int j = 0; j < 2; ++j) {
            acc[0][j] = __builtin_amdgcn_mfma_f32_16x16x32_bf16(af[0][0], wf[j][0], hhf[0][j], 0, 0, 0);
            acc[1][j] = __builtin_amdgcn_mfma_f32_16x16x32_bf16(af[1][0], wf[j][0], hhf[1][j], 0, 0, 0);
        }
        #pragma unroll
        for (int kt = 1; kt < 4; ++kt)
            #pragma unroll
            for (int j = 0; j < 2; ++j) {
                acc[0][j] = __builtin_amdgcn_mfma_f32_16x16x32_bf16(af[0][kt], wf[j][kt], acc[0][j], 0, 0, 0);
                acc[1][j] = __builtin_amdgcn_mfma_f32_16x16x32_bf16(af[1][kt], wf[j][kt], acc[1][j], 0, 0, 0);
            }

        // ---- phase 2 (A only, pre-barrier): ig partials -> LDS, stage next chunk, prefetch
        if (isA) {
            if (c + 2 < NCHUNK) {
                n0 = *(const float4*)(xsrc + (long)(c + 2) * 4096);
                n1 = *(const float4*)(xsrc + (long)(c + 2) * 4096 + 4);
            }
            float* igw = &igs[(c & 1) * IGBUF + p * IGPAIR + (q * 4) * IGSTR + lr];
            #pragma unroll
            for (int mt = 0; mt < 2; ++mt)
                #pragma unroll
                for (int r = 0; r < 4; ++r) {
                    const float ai = acc[mt][0][r];              // gate i
                    const float ag = acc[mt][1][r];              // gate g
                    const float Ei = ex2(-K1 * ai);
                    const float Eg = ex2( K2 * ag);
                    igw[(mt * 16 + r) * IGSTR] =
                        (Eg - 1.0f) * rcpf((1.0f + Ei) * (Eg + 1.0f));  // sigm(i)*tanh(g)
                }
            if (c + 1 < NCHUNK)
                *(short8*)(lws + ((c + 1) & 1) * LBUF) = pack8(p0, p1);
        }
        __syncthreads();

        // ---- phase 3 (B only, post-barrier): finish cell, store h (and last-chunk h/c)
        if (!isA) {
            const float* igr = &igs[(c & 1) * IGBUF + p * IGPAIR + (q * 4) * IGSTR + lr];
            const long rbase = row0 + (long)c * 32;
            const bool last = (rbase == M_DIM - 32);
            #pragma unroll
            for (int mt = 0; mt < 2; ++mt)
                #pragma unroll
                for (int r = 0; r < 4; ++r) {
                    const long row = rbase + mt * 16 + q * 4 + r;
                    const float ig = igr[(mt * 16 + r) * IGSTR];
                    const float afv = acc[mt][0][r];             // gate f
                    const float ao  = acc[mt][1][r];             // gate o
                    const float Ef = ex2(-K1 * afv);
                    const float gf = rcpf(1.0f + Ef);            // sigm(f)
                    const float cc = __builtin_fmaf(gf, c0v[mt][r], ig);
                    const float Ec = ex2( K2 * cc);
                    const float Eo = ex2(-K1 * ao);
                    const float ot = (Ec - 1.0f) * rcpf((1.0f + Eo) * (Ec + 1.0f));  // sigm(o)*tanh(cc)
                    const float hv = ot + nzv[mt][r];
                    out[row * 128 + hcol] = hv;
                    if (last) {
                        const int b = mt * 16 + q * 4 + r;
                        out[TBH +        b * 128 + hcol] = hv;
                        out[TBH + 4096 + b * 128 + hcol] = cc;
                    }
                }
        } else {
            p0 = n0; p1 = n1;
        }
    }
}

extern "C" void kernel_launch(void* const* d_in, const int* in_sizes, int n_in,
                              void* d_out, int out_size, void* d_ws, size_t ws_size,
                              hipStream_t stream) {
    const float* X     = (const float*)d_in[0];
    const float* h0    = (const float*)d_in[1];
    const float* c0    = (const float*)d_in[2];
    const float* noise = (const float*)d_in[3];
    const float* W_ih  = (const float*)d_in[4];
    const float* W_hh  = (const float*)d_in[5];
    const float* b_ih  = (const float*)d_in[6];
    const float* b_hh  = (const float*)d_in[7];

    unsigned short* Wb = (unsigned short*)d_ws;              // [512*128] bf16 = 128 KB
    float* hh = (float*)((char*)d_ws + 512 * 128 * sizeof(unsigned short));  // 64 KB
    float* out = (float*)d_out;

    prep<<<dim3(96), dim3(256), 0, stream>>>(h0, W_hh, b_ih, b_hh, W_ih, Wb, hh);
    lstm_main<<<dim3(M_DIM / RPB), dim3(1024), 0, stream>>>(X, Wb, hh, c0, noise, out);
}

// Round 9
// 155.109 us; speedup vs baseline: 1.0041x; 1.0041x over previous
//
#include <hip/hip_runtime.h>
#include <hip/hip_bf16.h>

#define T_DIM 4096
#define B_DIM 32
#define H_DIM 128
#define M_DIM (T_DIM * B_DIM)        // 131072 GEMM rows (t*B + b)
#define G_DIM 512                    // 4*H gate columns
#define TBH   ((long)M_DIM * H_DIM)  // 16777216 output elements for `outputs`

#define RPB    512                   // rows per persistent block: 256 blocks = 1 block/CU
#define NCHUNK (RPB / 32)            // 16 chunks of 32 rows
#define LSTR   136                   // LDS row stride in shorts (128 + 8 pad = 272 B, bank-balanced)
#define LBUF   (32 * LSTR)           // one staging buffer (shorts)
#define IGSTR  20                    // ig row stride in floats (2-way bank alias only = free)
#define IGPAIR (32 * IGSTR)          // 640 floats per pair per buffer
#define IGBUF  (8 * IGPAIR)          // 5120 floats per buffer

typedef __attribute__((ext_vector_type(8))) short short8;    // 8 bf16 = 4 VGPRs (MFMA A/B frag)
typedef __attribute__((ext_vector_type(4))) short short4v;   // 4 bf16 = 8 bytes
typedef __attribute__((ext_vector_type(4))) float floatx4;   // MFMA C/D frag

__device__ __forceinline__ unsigned short f2bf_rne(float x) {
    union { float f; unsigned int u; } v; v.f = x;
    unsigned int r = v.u + 0x7FFFu + ((v.u >> 16) & 1u);   // round-nearest-even
    return (unsigned short)(r >> 16);
}
__device__ __forceinline__ unsigned short f2bf_rh(float x) {
    union { float f; unsigned int u; } v; v.f = x;
    return (unsigned short)((v.u + 0x8000u) >> 16);        // round-half-up (cheap, ~unbiased)
}
__device__ __forceinline__ float ex2(float x) { return __builtin_amdgcn_exp2f(x); }   // v_exp_f32
__device__ __forceinline__ float rcpf(float x) { return __builtin_amdgcn_rcpf(x); }   // v_rcp_f32
__device__ __forceinline__ short8 pack8(float4 f0, float4 f1) {
    short8 s;
    s[0] = (short)f2bf_rh(f0.x); s[1] = (short)f2bf_rh(f0.y);
    s[2] = (short)f2bf_rh(f0.z); s[3] = (short)f2bf_rh(f0.w);
    s[4] = (short)f2bf_rh(f1.x); s[5] = (short)f2bf_rh(f1.y);
    s[6] = (short)f2bf_rh(f1.z); s[7] = (short)f2bf_rh(f1.w);
    return s;
}

// blocks 0..31:  hh[b][g] = h0[b,:]·W_hh[g,:] + b_ih[g] + b_hh[g]   (fp32, 32x512)
// blocks 32..95: W_ih fp32 -> bf16 (RNE) into ws
__global__ void prep(const float* __restrict__ h0,
                     const float* __restrict__ W_hh,
                     const float* __restrict__ b_ih,
                     const float* __restrict__ b_hh,
                     const float* __restrict__ W_ih,
                     unsigned short* __restrict__ Wb,
                     float* __restrict__ hh) {
    const int tid = threadIdx.x;
    if (blockIdx.x < 32) {
        __shared__ float h0s[128];
        const int b = blockIdx.x;
        if (tid < 128) h0s[tid] = h0[b * 128 + tid];
        __syncthreads();
        for (int g = tid; g < G_DIM; g += 256) {
            float acc = b_ih[g] + b_hh[g];
            const float* wr = W_hh + g * 128;
            #pragma unroll 8
            for (int k = 0; k < 128; ++k) acc += wr[k] * h0s[k];
            hh[b * G_DIM + g] = acc;
        }
    } else {
        const int e = ((blockIdx.x - 32) * 256 + tid) * 4;   // 64*256*4 = 65536 elements
        float4 f = *(const float4*)(W_ih + e);
        short4v s;
        s[0] = (short)f2bf_rne(f.x); s[1] = (short)f2bf_rne(f.y);
        s[2] = (short)f2bf_rne(f.z); s[3] = (short)f2bf_rne(f.w);
        *(short4v*)(Wb + e) = s;
    }
}

// GATE-SPLIT WAVE-PAIR kernel: 256 blocks x 1024 threads = 16 waves -> 4 waves/SIMD.
// R8 post-mortem: __launch_bounds__(1024) defaulted to min-waves=2 -> VGPR capped at 64
// -> wf spilled to scratch (WRITE_SIZE +33 MB) yet still ran 50.7us at 33% occupancy.
// Cap model (fits R1/R2/R8): VGPR_cap = 512 / (min_waves_arg * waves_per_SIMD_per_block).
// Fix: (1024, 1) -> cap = 128 (block-size feasibility still forces <=128). Union register
// demand ~120 <= 128 -> no spill. Everything else identical to R8.
// Wave pair (w, w+8) owns h-cols [p*16,p*16+16), p = w&7.
//   wave A (w<8): gates {0=i, 2=g}; computes ig = sigm(i)*tanh(g) -> LDS handoff (3 trans),
//                 plus all X staging (pack8) and 2-chunk-deep global prefetch.
//   wave B (w>=8): gates {1=f, 3=o}; reads ig, computes cc/h (5 trans), all global stores.
// One barrier per chunk; ig double-buffered so A's writes (pre-barrier, chunk c) never
// collide with B's reads (post-barrier, chunk c): the same buffer is rewritten only in
// chunk c+2, after barrier(c+1), which B passes only after finishing its chunk-c reads.
__global__ __launch_bounds__(1024, 1) void lstm_main(
    const float* __restrict__ X,              // [M,128] fp32 input rows
    const unsigned short* __restrict__ W,     // [512,128] bf16 W_ih (pre-converted, B^T layout)
    const float* __restrict__ hh,             // [32,512] fp32 precomputed
    const float* __restrict__ c0,             // [32,128] fp32
    const float* __restrict__ noise,          // [32,128] fp32
    float* __restrict__ out)                  // fp32: outputs[M*128], h_last[4096], c_last[4096]
{
    __shared__ unsigned short Xs[2 * LBUF];   // 2 x 32 x 136 bf16 = 17408 B
    __shared__ float igs[2 * IGBUF];          // 2 x 8 pairs x 32 x 20 f32 = 40960 B

    const int tid  = threadIdx.x;
    const int w    = tid >> 6;       // wave 0..15
    const int lane = tid & 63;
    const int q    = lane >> 4;      // quad 0..3
    const int lr   = lane & 15;
    const bool isA = (w < 8);
    const int p    = w & 7;          // pair id
    const int bsel = w >> 3;         // 0 for A, 1 for B
    const int hcol = (p << 4) + lr;  // this pair's h-column, 0..127
    const long row0 = (long)blockIdx.x * RPB;

    // ---- one-time: W fragments for THIS WAVE'S 2 gates (j -> gate 2j+bsel)
    short8 wf[2][4];                 // 8 frags = 32 VGPRs
    #pragma unroll
    for (int j = 0; j < 2; ++j)
        #pragma unroll
        for (int kt = 0; kt < 4; ++kt)
            wf[j][kt] = *(const short8*)(W + (((j << 1) | bsel) * 128 + hcol) * 128 + kt * 32 + q * 8);

    // ---- one-time: hh seeds for the 2 gates; B also loads c0/noise
    floatx4 hhf[2][2];
    #pragma unroll
    for (int mt = 0; mt < 2; ++mt)
        #pragma unroll
        for (int j = 0; j < 2; ++j) {
            floatx4 a;
            #pragma unroll
            for (int r = 0; r < 4; ++r)
                a[r] = hh[(mt * 16 + q * 4 + r) * G_DIM + ((j << 1) | bsel) * 128 + hcol];
            hhf[mt][j] = a;
        }
    float c0v[2][4], nzv[2][4];
    if (!isA) {
        #pragma unroll
        for (int mt = 0; mt < 2; ++mt)
            #pragma unroll
            for (int r = 0; r < 4; ++r) {
                const int b = mt * 16 + q * 4 + r;
                c0v[mt][r] = c0[b * 128 + hcol];
                nzv[mt][r] = noise[b * 128 + hcol];
            }
    }

    // ---- staging (A waves = tid 0..511): thread handles 8 consecutive X elements per chunk
    const int srow = tid >> 4;            // 0..31 (valid for tid<512)
    const int scol = (tid & 15) << 3;     // 0,8,...,120
    const float* xsrc = X + (row0 + srow) * 128 + scol;
    unsigned short* lws = &Xs[srow * LSTR + scol];

    float4 p0 = {}, p1 = {}, n0 = {}, n1 = {};
    if (isA) {
        float4 f0 = *(const float4*)(xsrc);
        float4 f1 = *(const float4*)(xsrc + 4);
        *(short8*)lws = pack8(f0, f1);
        p0 = *(const float4*)(xsrc + 4096);       // chunk 1
        p1 = *(const float4*)(xsrc + 4096 + 4);
    }
    __syncthreads();

    const float K1 = 1.44269504f;        // log2(e)
    const float K2 = 2.88539008f;        // 2*log2(e)

    for (int c = 0; c < NCHUNK; ++c) {
        // ---- phase 1 (all waves): A frags from LDS, 16 MFMAs (2 gates x 2 mt x 4 kt)
        const unsigned short* rb = &Xs[(c & 1) * LBUF];
        short8 af[2][4];
        #pragma unroll
        for (int mt = 0; mt < 2; ++mt)
            #pragma unroll
            for (int kt = 0; kt < 4; ++kt)
                af[mt][kt] = *(const short8*)(rb + (mt * 16 + lr) * LSTR + kt * 32 + q * 8);

        floatx4 acc[2][2];
        #pragma unroll
        for (int j = 0; j < 2; ++j) {
            acc[0][j] = __builtin_amdgcn_mfma_f32_16x16x32_bf16(af[0][0], wf[j][0], hhf[0][j], 0, 0, 0);
            acc[1][j] = __builtin_amdgcn_mfma_f32_16x16x32_bf16(af[1][0], wf[j][0], hhf[1][j], 0, 0, 0);
        }
        #pragma unroll
        for (int kt = 1; kt < 4; ++kt)
            #pragma unroll
            for (int j = 0; j < 2; ++j) {
                acc[0][j] = __builtin_amdgcn_mfma_f32_16x16x32_bf16(af[0][kt], wf[j][kt], acc[0][j], 0, 0, 0);
                acc[1][j] = __builtin_amdgcn_mfma_f32_16x16x32_bf16(af[1][kt], wf[j][kt], acc[1][j], 0, 0, 0);
            }

        // ---- phase 2 (A only, pre-barrier): ig partials -> LDS, stage next chunk, prefetch
        if (isA) {
            if (c + 2 < NCHUNK) {
                n0 = *(const float4*)(xsrc + (long)(c + 2) * 4096);
                n1 = *(const float4*)(xsrc + (long)(c + 2) * 4096 + 4);
            }
            float* igw = &igs[(c & 1) * IGBUF + p * IGPAIR + (q * 4) * IGSTR + lr];
            #pragma unroll
            for (int mt = 0; mt < 2; ++mt)
                #pragma unroll
                for (int r = 0; r < 4; ++r) {
                    const float ai = acc[mt][0][r];              // gate i
                    const float ag = acc[mt][1][r];              // gate g
                    const float Ei = ex2(-K1 * ai);
                    const float Eg = ex2( K2 * ag);
                    igw[(mt * 16 + r) * IGSTR] =
                        (Eg - 1.0f) * rcpf((1.0f + Ei) * (Eg + 1.0f));  // sigm(i)*tanh(g)
                }
            if (c + 1 < NCHUNK)
                *(short8*)(lws + ((c + 1) & 1) * LBUF) = pack8(p0, p1);
        }
        __syncthreads();

        // ---- phase 3 (B only, post-barrier): finish cell, store h (and last-chunk h/c)
        if (!isA) {
            const float* igr = &igs[(c & 1) * IGBUF + p * IGPAIR + (q * 4) * IGSTR + lr];
            const long rbase = row0 + (long)c * 32;
            const bool last = (rbase == M_DIM - 32);
            #pragma unroll
            for (int mt = 0; mt < 2; ++mt)
                #pragma unroll
                for (int r = 0; r < 4; ++r) {
                    const long row = rbase + mt * 16 + q * 4 + r;
                    const float ig = igr[(mt * 16 + r) * IGSTR];
                    const float afv = acc[mt][0][r];             // gate f
                    const float ao  = acc[mt][1][r];             // gate o
                    const float Ef = ex2(-K1 * afv);
                    const float gf = rcpf(1.0f + Ef);            // sigm(f)
                    const float cc = __builtin_fmaf(gf, c0v[mt][r], ig);
                    const float Ec = ex2( K2 * cc);
                    const float Eo = ex2(-K1 * ao);
                    const float ot = (Ec - 1.0f) * rcpf((1.0f + Eo) * (Ec + 1.0f));  // sigm(o)*tanh(cc)
                    const float hv = ot + nzv[mt][r];
                    out[row * 128 + hcol] = hv;
                    if (last) {
                        const int b = mt * 16 + q * 4 + r;
                        out[TBH +        b * 128 + hcol] = hv;
                        out[TBH + 4096 + b * 128 + hcol] = cc;
                    }
                }
        } else {
            p0 = n0; p1 = n1;
        }
    }
}

extern "C" void kernel_launch(void* const* d_in, const int* in_sizes, int n_in,
                              void* d_out, int out_size, void* d_ws, size_t ws_size,
                              hipStream_t stream) {
    const float* X     = (const float*)d_in[0];
    const float* h0    = (const float*)d_in[1];
    const float* c0    = (const float*)d_in[2];
    const float* noise = (const float*)d_in[3];
    const float* W_ih  = (const float*)d_in[4];
    const float* W_hh  = (const float*)d_in[5];
    const float* b_ih  = (const float*)d_in[6];
    const float* b_hh  = (const float*)d_in[7];

    unsigned short* Wb = (unsigned short*)d_ws;              // [512*128] bf16 = 128 KB
    float* hh = (float*)((char*)d_ws + 512 * 128 * sizeof(unsigned short));  // 64 KB
    float* out = (float*)d_out;

    prep<<<dim3(96), dim3(256), 0, stream>>>(h0, W_hh, b_ih, b_hh, W_ih, Wb, hh);
    lstm_main<<<dim3(M_DIM / RPB), dim3(1024), 0, stream>>>(X, Wb, hh, c0, noise, out);
}